// Round 2
// baseline (3213.823 us; speedup 1.0000x reference)
//
#include <hip/hip_runtime.h>
#include <math.h>

#define NB 16
#define HH 80
#define WW 60
#define HWSZ (HH * WW)        // 4800
#define CC 256
#define MTOT (NB * HWSZ)      // 76800
#define KVF (16 * 8 * 32 * 32)     // KV floats
#define KSF (16 * 8 * 32)          // Ksum floats

__device__ __forceinline__ float elu1(float x) {
    return x > 0.f ? x + 1.f : expf(x);
}

// PE value for channel c at spatial index l  (quirk: div[j] = exp(-2j))
__device__ __forceinline__ float pe_val(int c, int l) {
    const int h = l / WW, w = l - h * WW;
    const int j = c >> 2, sel = c & 3;
    const float dv = expf(-2.0f * (float)j);
    const float pos = (sel < 2) ? (float)(w + 1) : (float)(h + 1);
    const float arg = pos * dv;
    return (sel & 1) ? cosf(arg) : sinf(arg);
}

// ---------------- PE add + [N,C,HW] -> [N,HW,C] transpose (for feat0 only) ----------------
__global__ __launch_bounds__(256) void add_pe_transpose(const float* __restrict__ in,
                                                        float* __restrict__ out)
{
    __shared__ float tile[32][33];
    const int n = blockIdx.z;
    const int c0 = blockIdx.y * 32;
    const int l0 = blockIdx.x * 32;
    const int tx = threadIdx.x, ty = threadIdx.y;
#pragma unroll
    for (int i = 0; i < 4; ++i) {
        const int cl = ty + i * 8;
        tile[cl][tx] = in[(size_t)n * CC * HWSZ + (size_t)(c0 + cl) * HWSZ + l0 + tx];
    }
    __syncthreads();
#pragma unroll
    for (int i = 0; i < 4; ++i) {
        const int ll = ty + i * 8;
        const int l = l0 + ll;
        const int c = c0 + tx;
        out[((size_t)n * HWSZ + l) * CC + c] = tile[tx][ll] + pe_val(c, l);
    }
}

// ---------------- [N,HW,C] -> [N,C,HW] transpose ----------------
__global__ __launch_bounds__(256) void out_transpose(const float* __restrict__ in,
                                                     float* __restrict__ out)
{
    __shared__ float tile[32][33];
    const int n = blockIdx.z;
    const int c0 = blockIdx.y * 32;
    const int l0 = blockIdx.x * 32;
    const int tx = threadIdx.x, ty = threadIdx.y;
#pragma unroll
    for (int i = 0; i < 4; ++i) {
        const int ll = ty + i * 8;
        tile[ll][tx] = in[((size_t)n * HWSZ + l0 + ll) * CC + c0 + tx];
    }
    __syncthreads();
#pragma unroll
    for (int i = 0; i < 4; ++i) {
        const int cl = ty + i * 8;
        out[(size_t)n * CC * HWSZ + (size_t)(c0 + cl) * HWSZ + l0 + tx] = tile[tx][cl];
    }
}

// ---------------- zero small buffer ----------------
__global__ __launch_bounds__(256) void zero_kernel(float* __restrict__ p, int n)
{
    const int i = blockIdx.x * 256 + threadIdx.x;
    if (i < n) p[i] = 0.f;
}

// ---------------- GEMM: C[M,256] = act( [A0|A1][M,K] @ B[K,256] ) ----------------
// A0/A1 row-major [M,256]; if A1 != null, K==512 and k>=256 reads A1[:,k-256].
// 64x64 tile, 256 threads, 4x4 register blocking.
__global__ __launch_bounds__(256) void gemm_k(const float* __restrict__ A0,
                                              const float* __restrict__ A1,
                                              const float* __restrict__ B,
                                              float* __restrict__ C,
                                              int K, int act)
{
    __shared__ float As[16][65];   // [k][m]
    __shared__ float Bs[16][64];   // [k][n]
    const int t = threadIdx.x;
    const int row0 = blockIdx.y * 64;
    const int col0 = blockIdx.x * 64;
    const int ty = t >> 4, tx = t & 15;
    const int am = t >> 2, ak = (t & 3) * 4;
    const int bk = t >> 4, bn = (t & 15) * 4;
    float acc[4][4] = {};
    for (int k0 = 0; k0 < K; k0 += 16) {
        const float* Asrc = (A1 != nullptr && k0 >= 256)
            ? (A1 + (size_t)(row0 + am) * 256 + (k0 - 256) + ak)
            : (A0 + (size_t)(row0 + am) * 256 + k0 + ak);
        const float4 av = *(const float4*)Asrc;
        const float4 bv = *(const float4*)&B[(size_t)(k0 + bk) * 256 + col0 + bn];
        As[ak + 0][am] = av.x;
        As[ak + 1][am] = av.y;
        As[ak + 2][am] = av.z;
        As[ak + 3][am] = av.w;
        *(float4*)&Bs[bk][bn] = bv;
        __syncthreads();
#pragma unroll
        for (int kk = 0; kk < 16; ++kk) {
            const float a0 = As[kk][ty * 4 + 0];
            const float a1 = As[kk][ty * 4 + 1];
            const float a2 = As[kk][ty * 4 + 2];
            const float a3 = As[kk][ty * 4 + 3];
            const float4 b4 = *(const float4*)&Bs[kk][tx * 4];
            acc[0][0] += a0 * b4.x; acc[0][1] += a0 * b4.y; acc[0][2] += a0 * b4.z; acc[0][3] += a0 * b4.w;
            acc[1][0] += a1 * b4.x; acc[1][1] += a1 * b4.y; acc[1][2] += a1 * b4.z; acc[1][3] += a1 * b4.w;
            acc[2][0] += a2 * b4.x; acc[2][1] += a2 * b4.y; acc[2][2] += a2 * b4.z; acc[2][3] += a2 * b4.w;
            acc[3][0] += a3 * b4.x; acc[3][1] += a3 * b4.y; acc[3][2] += a3 * b4.z; acc[3][3] += a3 * b4.w;
        }
        __syncthreads();
    }
#pragma unroll
    for (int i = 0; i < 4; ++i) {
        float4 o;
        o.x = acc[i][0]; o.y = acc[i][1]; o.z = acc[i][2]; o.w = acc[i][3];
        if (act) {
            o.x = fmaxf(o.x, 0.f); o.y = fmaxf(o.y, 0.f);
            o.z = fmaxf(o.z, 0.f); o.w = fmaxf(o.w, 0.f);
        }
        *(float4*)&C[(size_t)(row0 + ty * 4 + i) * 256 + col0 + tx * 4] = o;
    }
}

// ---------------- GEMM with A = transpose(feat NCHW) + PE  (k/v projections) ----------------
// C[M,256] = (featT+PE)[M,256] @ B[256,256]. Avoids materializing f1.
__global__ __launch_bounds__(256) void gemm_pe(const float* __restrict__ feat,
                                               const float* __restrict__ B,
                                               float* __restrict__ C)
{
    __shared__ float As[16][65];   // [k][m]
    __shared__ float Bs[16][64];
    const int t = threadIdx.x;
    const int row0 = blockIdx.y * 64;
    const int col0 = blockIdx.x * 64;
    const int n = row0 / HWSZ;         // 4800 % 64 == 0 -> tile within one n
    const int l0 = row0 - n * HWSZ;
    const int ty = t >> 4, tx = t & 15;
    const int lk = t >> 4;             // c offset 0..15
    const int lm = (t & 15) * 4;       // l offset, float4 along l
    // spatial coords fixed per thread
    float px[4], py[4];
#pragma unroll
    for (int e = 0; e < 4; ++e) {
        const int l = l0 + lm + e;
        const int h = l / WW, w = l - h * WW;
        px[e] = (float)(w + 1);
        py[e] = (float)(h + 1);
    }
    const int bk = t >> 4, bn = (t & 15) * 4;
    float acc[4][4] = {};
    for (int k0 = 0; k0 < 256; k0 += 16) {
        const int c = k0 + lk;
        const int j = c >> 2, sel = c & 3;
        const float dv = expf(-2.0f * (float)j);
        const float4 av = *(const float4*)&feat[(size_t)n * CC * HWSZ + (size_t)c * HWSZ + l0 + lm];
        float a[4] = {av.x, av.y, av.z, av.w};
#pragma unroll
        for (int e = 0; e < 4; ++e) {
            const float arg = ((sel < 2) ? px[e] : py[e]) * dv;
            const float pe = (sel & 1) ? cosf(arg) : sinf(arg);
            As[lk][lm + e] = a[e] + pe;
        }
        const float4 bv = *(const float4*)&B[(size_t)(k0 + bk) * 256 + col0 + bn];
        *(float4*)&Bs[bk][bn] = bv;
        __syncthreads();
#pragma unroll
        for (int kk = 0; kk < 16; ++kk) {
            const float a0 = As[kk][ty * 4 + 0];
            const float a1 = As[kk][ty * 4 + 1];
            const float a2 = As[kk][ty * 4 + 2];
            const float a3 = As[kk][ty * 4 + 3];
            const float4 b4 = *(const float4*)&Bs[kk][tx * 4];
            acc[0][0] += a0 * b4.x; acc[0][1] += a0 * b4.y; acc[0][2] += a0 * b4.z; acc[0][3] += a0 * b4.w;
            acc[1][0] += a1 * b4.x; acc[1][1] += a1 * b4.y; acc[1][2] += a1 * b4.z; acc[1][3] += a1 * b4.w;
            acc[2][0] += a2 * b4.x; acc[2][1] += a2 * b4.y; acc[2][2] += a2 * b4.z; acc[2][3] += a2 * b4.w;
            acc[3][0] += a3 * b4.x; acc[3][1] += a3 * b4.y; acc[3][2] += a3 * b4.z; acc[3][3] += a3 * b4.w;
        }
        __syncthreads();
    }
#pragma unroll
    for (int i = 0; i < 4; ++i) {
        float4 o;
        o.x = acc[i][0]; o.y = acc[i][1]; o.z = acc[i][2]; o.w = acc[i][3];
        *(float4*)&C[(size_t)(row0 + ty * 4 + i) * 256 + col0 + tx * 4] = o;
    }
}

// ---------------- KV = sum_s K'[s,d] V'[s,e] ; Ksum[d] = sum_s K'[s,d] ----------------
#define SCHUNK 480
__global__ __launch_bounds__(256) void kv_kernel(const float* __restrict__ kbuf,
                                                 const float* __restrict__ vbuf,
                                                 float* __restrict__ KV,
                                                 float* __restrict__ Ksum)
{
    __shared__ float Kls[16][32];
    __shared__ float Vls[16][32];
    const int n = blockIdx.z, h = blockIdx.y;
    const int s0 = blockIdx.x * SCHUNK;
    const int t = threadIdx.x;
    const int lr = t >> 5;
    const int lc = t & 31;
    const int d = t >> 3;
    const int e0 = (t & 7) * 4;
    const float invS = 1.0f / 4800.0f;
    float acc0 = 0.f, acc1 = 0.f, acc2 = 0.f, acc3 = 0.f, ks = 0.f;
    for (int it = 0; it < SCHUNK / 16; ++it) {
        const int sb = s0 + it * 16;
#pragma unroll
        for (int rr = 0; rr < 2; ++rr) {
            const int s = sb + lr + rr * 8;
            const size_t base = ((size_t)(n * HWSZ + s)) * 256 + h * 32 + lc;
            Kls[lr + rr * 8][lc] = elu1(kbuf[base]);
            Vls[lr + rr * 8][lc] = vbuf[base] * invS;
        }
        __syncthreads();
#pragma unroll
        for (int ss = 0; ss < 16; ++ss) {
            const float kval = Kls[ss][d];
            acc0 += kval * Vls[ss][e0 + 0];
            acc1 += kval * Vls[ss][e0 + 1];
            acc2 += kval * Vls[ss][e0 + 2];
            acc3 += kval * Vls[ss][e0 + 3];
            if (e0 == 0) ks += kval;
        }
        __syncthreads();
    }
    float* kvp = KV + ((size_t)(n * 8 + h) * 32 + d) * 32 + e0;
    atomicAdd(kvp + 0, acc0);
    atomicAdd(kvp + 1, acc1);
    atomicAdd(kvp + 2, acc2);
    atomicAdd(kvp + 3, acc3);
    if (e0 == 0) atomicAdd(&Ksum[(size_t)(n * 8 + h) * 32 + d], ks);
}

// ---------------- attention apply, in place on q ----------------
__global__ __launch_bounds__(256) void attn_apply(float* __restrict__ q,
                                                  const float* __restrict__ KV,
                                                  const float* __restrict__ Ksum)
{
    const int row = blockIdx.x;
    const int n = row / HWSZ;
    const int t = threadIdx.x;
    __shared__ float Qls[256];
    Qls[t] = elu1(q[(size_t)row * 256 + t]);
    __syncthreads();
    const int h = t >> 5, e = t & 31;
    const float* kvp = KV + (size_t)(n * 8 + h) * 32 * 32;
    const float* ksp = Ksum + (size_t)(n * 8 + h) * 32;
    float zden = 1e-6f, acc = 0.f;
#pragma unroll
    for (int d = 0; d < 32; ++d) {
        const float qd = Qls[h * 32 + d];
        zden += qd * ksp[d];
        acc += qd * kvp[d * 32 + e];
    }
    q[(size_t)row * 256 + t] = acc * (4800.0f / zden);
}

// ---------------- LayerNorm over last dim (256); optional residual output ----------------
__device__ __forceinline__ float block_sum256(float v, float* sdata)
{
    const int t = threadIdx.x;
#pragma unroll
    for (int off = 32; off > 0; off >>= 1) v += __shfl_down(v, off, 64);
    if ((t & 63) == 0) sdata[t >> 6] = v;
    __syncthreads();
    const float r = sdata[0] + sdata[1] + sdata[2] + sdata[3];
    __syncthreads();
    return r;
}

__global__ __launch_bounds__(256) void ln_kernel(float* __restrict__ x,
                                                 const float* __restrict__ g,
                                                 const float* __restrict__ b,
                                                 float* __restrict__ resid)
{
    __shared__ float sdata[4];
    const int row = blockIdx.x;
    const int t = threadIdx.x;
    const size_t idx = (size_t)row * 256 + t;
    const float v = x[idx];
    const float mu = block_sum256(v, sdata) * (1.0f / 256.0f);
    const float dd = v - mu;
    const float var = block_sum256(dd * dd, sdata) * (1.0f / 256.0f);
    const float y = dd * rsqrtf(var + 1e-5f) * g[t] + b[t];
    if (resid != nullptr) resid[idx] += y;
    else x[idx] = y;
}

// ---------------- launch ----------------
extern "C" void kernel_launch(void* const* d_in, const int* in_sizes, int n_in,
                              void* d_out, int out_size, void* d_ws, size_t ws_size,
                              hipStream_t stream)
{
    const float* feat0 = (const float*)d_in[0];
    const float* feat1 = (const float*)d_in[1];
    const float* Wq = (const float*)d_in[2];
    const float* Wk = (const float*)d_in[3];
    const float* Wv = (const float*)d_in[4];
    const float* Wm = (const float*)d_in[5];
    const float* W1 = (const float*)d_in[6];
    const float* W2 = (const float*)d_in[7];
    const float* g1 = (const float*)d_in[8];
    const float* b1 = (const float*)d_in[9];
    const float* g2 = (const float*)d_in[10];
    const float* b2 = (const float*)d_in[11];

    float* ws = (float*)d_ws;
    const size_t BUF = (size_t)MTOT * 256;   // 19,660,800 floats (78.6 MB)
    float* f0   = ws;                        // persistent activation
    float* kb   = ws + BUF;                  // scratch A
    float* KV   = ws + 2 * BUF;              // small
    float* Ksum = KV + KVF;
    float* vb   = (float*)d_out;             // scratch B (d_out reused; fully rewritten at end)
    // total ws: 2*BUF + KVF + KSF floats = ~157.8 MB

    const dim3 tb(32, 8);
    const dim3 tgrid(HWSZ / 32, CC / 32, NB);
    add_pe_transpose<<<tgrid, tb, 0, stream>>>(feat0, f0);

    const dim3 ggrid(4, MTOT / 64);          // (4, 1200)

    for (int i = 0; i < 2; ++i) {
        const float* Wqi = Wq + (size_t)i * 256 * 256;
        const float* Wki = Wk + (size_t)i * 256 * 256;
        const float* Wvi = Wv + (size_t)i * 256 * 256;
        const float* Wmi = Wm + (size_t)i * 256 * 256;
        const float* W1i = W1 + (size_t)i * 512 * 256;
        const float* W2i = W2 + (size_t)i * 256 * 256;

        // k = (feat1T+PE)@Wk -> kb ; v = (feat1T+PE)@Wv -> vb
        gemm_pe<<<ggrid, 256, 0, stream>>>(feat1, Wki, kb);
        gemm_pe<<<ggrid, 256, 0, stream>>>(feat1, Wvi, vb);

        // KV / Ksum reduction (zero first; ws is poisoned每 launch)
        zero_kernel<<<(KVF + KSF + 255) / 256, 256, 0, stream>>>(KV, KVF + KSF);
        kv_kernel<<<dim3(HWSZ / SCHUNK, 8, NB), 256, 0, stream>>>(kb, vb, KV, Ksum);

        // q = f0@Wq -> kb (kv_kernel already consumed kb), attention in place
        gemm_k<<<ggrid, 256, 0, stream>>>(f0, nullptr, Wqi, kb, 256, 0);
        attn_apply<<<MTOT, 256, 0, stream>>>(kb, KV, Ksum);

        // msg = attn@Wm -> vb ; LN1 in place
        gemm_k<<<ggrid, 256, 0, stream>>>(kb, nullptr, Wmi, vb, 256, 0);
        ln_kernel<<<MTOT, 256, 0, stream>>>(vb, g1 + i * 256, b1 + i * 256, nullptr);

        // hidden = relu([f0|msg]@W1) -> kb ; msg2 = hidden@W2 -> vb ; LN2 + residual into f0
        gemm_k<<<ggrid, 256, 0, stream>>>(f0, vb, W1i, kb, 512, 1);
        gemm_k<<<ggrid, 256, 0, stream>>>(kb, nullptr, W2i, vb, 256, 0);
        ln_kernel<<<MTOT, 256, 0, stream>>>(vb, g2 + i * 256, b2 + i * 256, f0);
    }

    out_transpose<<<tgrid, tb, 0, stream>>>(f0, (float*)d_out);
}

// Round 3
// 1274.935 us; speedup vs baseline: 2.5208x; 2.5208x over previous
//
#include <hip/hip_runtime.h>
#include <math.h>

#define NB 16
#define HH 80
#define WW 60
#define HWSZ (HH * WW)        // 4800
#define CC 256
#define MTOT (NB * HWSZ)      // 76800
#define KVF (16 * 8 * 32 * 32)
#define KSF (16 * 8 * 32)
#define BUF ((size_t)MTOT * CC)   // 19,660,800 elements

typedef unsigned short u16;
typedef __attribute__((ext_vector_type(8))) short short8;
typedef __attribute__((ext_vector_type(4))) float floatx4;

__device__ __forceinline__ float bf2f(u16 u) {
    union { unsigned int i; float f; } v; v.i = ((unsigned int)u) << 16; return v.f;
}
__device__ __forceinline__ u16 f2bf(float f) {
    union { unsigned int i; float f; } v; v.f = f;
    unsigned int u = v.i;
    u += 0x7FFFu + ((u >> 16) & 1u);          // round-to-nearest-even
    return (u16)(u >> 16);
}
__device__ __forceinline__ float elu1(float x) { return x > 0.f ? x + 1.f : expf(x); }

// PE value for channel c at spatial index l (quirk: div[j] = exp(-2j))
__device__ __forceinline__ float pe_val(int c, int l) {
    const int h = l / WW, w = l - h * WW;
    const int j = c >> 2, sel = c & 3;
    const float dv = expf(-2.0f * (float)j);
    const float pos = (sel < 2) ? (float)(w + 1) : (float)(h + 1);
    const float arg = pos * dv;
    return (sel & 1) ? cosf(arg) : sinf(arg);
}

// ---------------- PE add + [N,C,HW] -> [N,HW,C]; fp32 out optional, bf16 out always ----------------
__global__ __launch_bounds__(256) void add_pe_transpose(const float* __restrict__ in,
                                                        float* __restrict__ outf,
                                                        u16* __restrict__ outb)
{
    __shared__ float tile[32][33];
    const int n = blockIdx.z;
    const int c0 = blockIdx.y * 32;
    const int l0 = blockIdx.x * 32;
    const int tx = threadIdx.x, ty = threadIdx.y;
#pragma unroll
    for (int i = 0; i < 4; ++i) {
        const int cl = ty + i * 8;
        tile[cl][tx] = in[(size_t)n * CC * HWSZ + (size_t)(c0 + cl) * HWSZ + l0 + tx];
    }
    __syncthreads();
#pragma unroll
    for (int i = 0; i < 4; ++i) {
        const int ll = ty + i * 8;
        const int l = l0 + ll;
        const int c = c0 + tx;
        const float val = tile[tx][ll] + pe_val(c, l);
        const size_t idx = ((size_t)n * HWSZ + l) * CC + c;
        if (outf) outf[idx] = val;
        outb[idx] = f2bf(val);
    }
}

// ---------------- [N,HW,C] fp32 -> [N,C,HW] fp32 ----------------
__global__ __launch_bounds__(256) void out_transpose(const float* __restrict__ in,
                                                     float* __restrict__ out)
{
    __shared__ float tile[32][33];
    const int n = blockIdx.z;
    const int c0 = blockIdx.y * 32;
    const int l0 = blockIdx.x * 32;
    const int tx = threadIdx.x, ty = threadIdx.y;
#pragma unroll
    for (int i = 0; i < 4; ++i) {
        const int ll = ty + i * 8;
        tile[ll][tx] = in[((size_t)n * HWSZ + l0 + ll) * CC + c0 + tx];
    }
    __syncthreads();
#pragma unroll
    for (int i = 0; i < 4; ++i) {
        const int cl = ty + i * 8;
        out[(size_t)n * CC * HWSZ + (size_t)(c0 + cl) * HWSZ + l0 + tx] = tile[tx][cl];
    }
}

// ---------------- weight fp32 [K,256] -> bf16 transposed [256,K] ----------------
__global__ __launch_bounds__(256) void convert_wt(const float* __restrict__ W,
                                                  u16* __restrict__ WT, int K)
{
    __shared__ float tile[32][33];
    const int k0 = blockIdx.x * 32;
    const int n0 = blockIdx.y * 32;
    const int tx = threadIdx.x, ty = threadIdx.y;
#pragma unroll
    for (int i = 0; i < 4; ++i)
        tile[ty + i * 8][tx] = W[(size_t)(k0 + ty + i * 8) * 256 + n0 + tx];
    __syncthreads();
#pragma unroll
    for (int i = 0; i < 4; ++i)
        WT[(size_t)(n0 + ty + i * 8) * K + k0 + tx] = f2bf(tile[tx][ty + i * 8]);
}

// ---------------- zero small buffer ----------------
__global__ __launch_bounds__(256) void zero_kernel(float* __restrict__ p, int n)
{
    const int i = blockIdx.x * 256 + threadIdx.x;
    if (i < n) p[i] = 0.f;
}

// ---------------- MFMA GEMM: C_bf16[M,256] = act( [A0|A1][M,K]_bf16 @ W[K,256] ) ----------------
// WT is W transposed bf16 [256,K]. 128x128 tile, 4 waves, each 4x4 of 16x16x32 MFMA.
__global__ __launch_bounds__(256) void gemm_mfma(const u16* __restrict__ A0,
                                                 const u16* __restrict__ A1,
                                                 const u16* __restrict__ WT,
                                                 u16* __restrict__ C,
                                                 int K, int relu)
{
    __shared__ u16 As[128 * 32];
    __shared__ u16 Bs[128 * 32];
    const int t = threadIdx.x;
    const int row0 = blockIdx.y * 128;
    const int col0 = blockIdx.x * 128;
    const int w = t >> 6, lane = t & 63;
    const int wr = (w >> 1) * 64, wc = (w & 1) * 64;
    const int quad = lane >> 4, lrow = lane & 15;
    const int sm = t >> 2, skc = (t & 3) * 8;   // staging: thread covers rows sm & sm+64, 8 bf16 each

    const floatx4 zero = {0.f, 0.f, 0.f, 0.f};
    floatx4 acc[4][4];
#pragma unroll
    for (int i = 0; i < 4; ++i)
#pragma unroll
        for (int j = 0; j < 4; ++j) acc[i][j] = zero;

    const size_t arow0 = (size_t)(row0 + sm) * 256 + skc;
    const size_t arow1 = (size_t)(row0 + 64 + sm) * 256 + skc;
    const size_t brow0 = (size_t)(col0 + sm) * K + skc;
    const size_t brow1 = (size_t)(col0 + 64 + sm) * K + skc;

    // prefetch k0 = 0 (always from A0)
    uint4 ra0 = *(const uint4*)(A0 + arow0);
    uint4 ra1 = *(const uint4*)(A0 + arow1);
    uint4 rb0 = *(const uint4*)(WT + brow0);
    uint4 rb1 = *(const uint4*)(WT + brow1);

    for (int k0 = 0; k0 < K; k0 += 32) {
        __syncthreads();
        *(uint4*)&As[sm * 32 + skc] = ra0;
        *(uint4*)&As[(64 + sm) * 32 + skc] = ra1;
        *(uint4*)&Bs[sm * 32 + skc] = rb0;
        *(uint4*)&Bs[(64 + sm) * 32 + skc] = rb1;
        __syncthreads();
        const int kn = k0 + 32;
        if (kn < K) {
            const u16* Abn = (A1 != nullptr && kn >= 256) ? (A1 + (kn - 256)) : (A0 + kn);
            ra0 = *(const uint4*)(Abn + arow0);
            ra1 = *(const uint4*)(Abn + arow1);
            rb0 = *(const uint4*)(WT + brow0 + kn);
            rb1 = *(const uint4*)(WT + brow1 + kn);
        }
        short8 af[4], bfv[4];
#pragma unroll
        for (int i = 0; i < 4; ++i) {
            af[i]  = *(const short8*)&As[(wr + i * 16 + lrow) * 32 + quad * 8];
            bfv[i] = *(const short8*)&Bs[(wc + i * 16 + lrow) * 32 + quad * 8];
        }
#pragma unroll
        for (int i = 0; i < 4; ++i)
#pragma unroll
            for (int j = 0; j < 4; ++j)
                acc[i][j] = __builtin_amdgcn_mfma_f32_16x16x32_bf16(af[i], bfv[j], acc[i][j], 0, 0, 0);
    }

#pragma unroll
    for (int i = 0; i < 4; ++i) {
        const int rbase = row0 + wr + i * 16 + quad * 4;
#pragma unroll
        for (int j = 0; j < 4; ++j) {
            const int cc = col0 + wc + j * 16 + lrow;
#pragma unroll
            for (int r = 0; r < 4; ++r) {
                float x = acc[i][j][r];
                if (relu) x = fmaxf(x, 0.f);
                C[(size_t)(rbase + r) * 256 + cc] = f2bf(x);
            }
        }
    }
}

// ---------------- KV = sum_s K'[s,d] V'[s,e] ; Ksum[d] = sum_s K'[s,d] (bf16 in) ----------------
#define SCHUNK 480
__global__ __launch_bounds__(256) void kv_kernel(const u16* __restrict__ kbuf,
                                                 const u16* __restrict__ vbuf,
                                                 float* __restrict__ KV,
                                                 float* __restrict__ Ksum)
{
    __shared__ float Kls[16][32];
    __shared__ float Vls[16][32];
    const int n = blockIdx.z, h = blockIdx.y;
    const int s0 = blockIdx.x * SCHUNK;
    const int t = threadIdx.x;
    const int lr = t >> 5;
    const int lc = t & 31;
    const int d = t >> 3;
    const int e0 = (t & 7) * 4;
    const float invS = 1.0f / 4800.0f;
    float acc0 = 0.f, acc1 = 0.f, acc2 = 0.f, acc3 = 0.f, ks = 0.f;
    for (int it = 0; it < SCHUNK / 16; ++it) {
        const int sb = s0 + it * 16;
#pragma unroll
        for (int rr = 0; rr < 2; ++rr) {
            const int s = sb + lr + rr * 8;
            const size_t base = ((size_t)(n * HWSZ + s)) * 256 + h * 32 + lc;
            Kls[lr + rr * 8][lc] = elu1(bf2f(kbuf[base]));
            Vls[lr + rr * 8][lc] = bf2f(vbuf[base]) * invS;
        }
        __syncthreads();
#pragma unroll
        for (int ss = 0; ss < 16; ++ss) {
            const float kval = Kls[ss][d];
            acc0 += kval * Vls[ss][e0 + 0];
            acc1 += kval * Vls[ss][e0 + 1];
            acc2 += kval * Vls[ss][e0 + 2];
            acc3 += kval * Vls[ss][e0 + 3];
            if (e0 == 0) ks += kval;
        }
        __syncthreads();
    }
    float* kvp = KV + ((size_t)(n * 8 + h) * 32 + d) * 32 + e0;
    atomicAdd(kvp + 0, acc0);
    atomicAdd(kvp + 1, acc1);
    atomicAdd(kvp + 2, acc2);
    atomicAdd(kvp + 3, acc3);
    if (e0 == 0) atomicAdd(&Ksum[(size_t)(n * 8 + h) * 32 + d], ks);
}

// ---------------- attention apply, in place on q (bf16) ----------------
__global__ __launch_bounds__(256) void attn_apply(u16* __restrict__ q,
                                                  const float* __restrict__ KV,
                                                  const float* __restrict__ Ksum)
{
    const int row = blockIdx.x;
    const int n = row / HWSZ;
    const int t = threadIdx.x;
    __shared__ float Qls[256];
    const size_t idx = (size_t)row * 256 + t;
    Qls[t] = elu1(bf2f(q[idx]));
    __syncthreads();
    const int h = t >> 5, e = t & 31;
    const float* kvp = KV + (size_t)(n * 8 + h) * 32 * 32;
    const float* ksp = Ksum + (size_t)(n * 8 + h) * 32;
    float zden = 1e-6f, acc = 0.f;
#pragma unroll
    for (int d = 0; d < 32; ++d) {
        const float qd = Qls[h * 32 + d];
        zden += qd * ksp[d];
        acc += qd * kvp[d * 32 + e];
    }
    q[idx] = f2bf(acc * (4800.0f / zden));
}

// ---------------- LayerNorm helpers ----------------
__device__ __forceinline__ float block_sum256(float v, float* sdata)
{
    const int t = threadIdx.x;
#pragma unroll
    for (int off = 32; off > 0; off >>= 1) v += __shfl_down(v, off, 64);
    if ((t & 63) == 0) sdata[t >> 6] = v;
    __syncthreads();
    const float r = sdata[0] + sdata[1] + sdata[2] + sdata[3];
    __syncthreads();
    return r;
}

// LN in place on bf16 buffer
__global__ __launch_bounds__(256) void ln_inplace(u16* __restrict__ x,
                                                  const float* __restrict__ g,
                                                  const float* __restrict__ b)
{
    __shared__ float sdata[4];
    const int row = blockIdx.x;
    const int t = threadIdx.x;
    const size_t idx = (size_t)row * 256 + t;
    const float v = bf2f(x[idx]);
    const float mu = block_sum256(v, sdata) * (1.0f / 256.0f);
    const float dd = v - mu;
    const float var = block_sum256(dd * dd, sdata) * (1.0f / 256.0f);
    x[idx] = f2bf(dd * rsqrtf(var + 1e-5f) * g[t] + b[t]);
}

// LN(x_bf16) added into fp32 residual f0; also refresh f0b (bf16 mirror)
__global__ __launch_bounds__(256) void ln_resid(const u16* __restrict__ x,
                                                const float* __restrict__ g,
                                                const float* __restrict__ b,
                                                float* __restrict__ f0,
                                                u16* __restrict__ f0b)
{
    __shared__ float sdata[4];
    const int row = blockIdx.x;
    const int t = threadIdx.x;
    const size_t idx = (size_t)row * 256 + t;
    const float v = bf2f(x[idx]);
    const float mu = block_sum256(v, sdata) * (1.0f / 256.0f);
    const float dd = v - mu;
    const float var = block_sum256(dd * dd, sdata) * (1.0f / 256.0f);
    const float y = dd * rsqrtf(var + 1e-5f) * g[t] + b[t];
    const float nf = f0[idx] + y;
    f0[idx] = nf;
    f0b[idx] = f2bf(nf);
}

// ---------------- launch ----------------
extern "C" void kernel_launch(void* const* d_in, const int* in_sizes, int n_in,
                              void* d_out, int out_size, void* d_ws, size_t ws_size,
                              hipStream_t stream)
{
    const float* feat0 = (const float*)d_in[0];
    const float* feat1 = (const float*)d_in[1];
    const float* Wq = (const float*)d_in[2];
    const float* Wk = (const float*)d_in[3];
    const float* Wv = (const float*)d_in[4];
    const float* Wm = (const float*)d_in[5];
    const float* W1 = (const float*)d_in[6];
    const float* W2 = (const float*)d_in[7];
    const float* g1 = (const float*)d_in[8];
    const float* b1 = (const float*)d_in[9];
    const float* g2 = (const float*)d_in[10];
    const float* b2 = (const float*)d_in[11];

    float* ws = (float*)d_ws;
    float* KV = ws;
    float* Ksum = KV + KVF;
    u16* Wb = (u16*)(Ksum + KSF);                 // 2 * 458752 bf16 weights
    const size_t WBE = 458752;                    // bf16 elements per layer
    float* f0 = ws + (KVF + KSF) + WBE;           // fp32 residual master (WBE u16 = WBE/2... overallocated to WBE floats for alignment safety)
    u16* f0b = (u16*)(f0 + BUF);                  // bf16 mirror of f0
    u16* f1b = f0b + BUF;                         // bf16 (feat1T + PE)
    u16* kb16 = (u16*)d_out;                      // scratch A (bf16) in d_out
    u16* vb16 = kb16 + BUF;                       // scratch B (bf16) in d_out
    // ws usage: (135168 + 458752 + BUF)*4 + 2*BUF*2 ≈ 159 MB

    const dim3 tb(32, 8);
    const dim3 tgrid(HWSZ / 32, CC / 32, NB);
    add_pe_transpose<<<tgrid, tb, 0, stream>>>(feat0, f0, f0b);
    add_pe_transpose<<<tgrid, tb, 0, stream>>>(feat1, nullptr, f1b);

    // convert all weights to bf16, transposed to [N,K]
    for (int i = 0; i < 2; ++i) {
        u16* WqT = Wb + (size_t)i * WBE;
        u16* WkT = WqT + 65536;
        u16* WvT = WkT + 65536;
        u16* WmT = WvT + 65536;
        u16* W1T = WmT + 65536;
        u16* W2T = W1T + 131072;
        convert_wt<<<dim3(8, 8),  tb, 0, stream>>>(Wq + (size_t)i * 65536,  WqT, 256);
        convert_wt<<<dim3(8, 8),  tb, 0, stream>>>(Wk + (size_t)i * 65536,  WkT, 256);
        convert_wt<<<dim3(8, 8),  tb, 0, stream>>>(Wv + (size_t)i * 65536,  WvT, 256);
        convert_wt<<<dim3(8, 8),  tb, 0, stream>>>(Wm + (size_t)i * 65536,  WmT, 256);
        convert_wt<<<dim3(16, 8), tb, 0, stream>>>(W1 + (size_t)i * 131072, W1T, 512);
        convert_wt<<<dim3(8, 8),  tb, 0, stream>>>(W2 + (size_t)i * 65536,  W2T, 256);
    }

    const dim3 ggrid(2, MTOT / 128);              // (2, 600)
    for (int i = 0; i < 2; ++i) {
        u16* WqT = Wb + (size_t)i * WBE;
        u16* WkT = WqT + 65536;
        u16* WvT = WkT + 65536;
        u16* WmT = WvT + 65536;
        u16* W1T = WmT + 65536;
        u16* W2T = W1T + 131072;

        // k, v projections from f1b
        gemm_mfma<<<ggrid, 256, 0, stream>>>(f1b, nullptr, WkT, kb16, 256, 0);
        gemm_mfma<<<ggrid, 256, 0, stream>>>(f1b, nullptr, WvT, vb16, 256, 0);

        // KV / Ksum reduction
        zero_kernel<<<(KVF + KSF + 255) / 256, 256, 0, stream>>>(KV, KVF + KSF);
        kv_kernel<<<dim3(HWSZ / SCHUNK, 8, NB), 256, 0, stream>>>(kb16, vb16, KV, Ksum);

        // q projection + attention in place
        gemm_mfma<<<ggrid, 256, 0, stream>>>(f0b, nullptr, WqT, kb16, 256, 0);
        attn_apply<<<MTOT, 256, 0, stream>>>(kb16, KV, Ksum);

        // msg = attn @ Wm ; LN1 in place
        gemm_mfma<<<ggrid, 256, 0, stream>>>(kb16, nullptr, WmT, vb16, 256, 0);
        ln_inplace<<<MTOT, 256, 0, stream>>>(vb16, g1 + i * 256, b1 + i * 256);

        // hidden = relu([f0|msg]@W1) ; msg2 = hidden@W2 ; LN2 + residual
        gemm_mfma<<<ggrid, 256, 0, stream>>>(f0b, vb16, W1T, kb16, 512, 1);
        gemm_mfma<<<ggrid, 256, 0, stream>>>(kb16, nullptr, W2T, vb16, 256, 0);
        ln_resid<<<MTOT, 256, 0, stream>>>(vb16, g2 + i * 256, b2 + i * 256, f0, f0b);
    }

    out_transpose<<<tgrid, tb, 0, stream>>>(f0, (float*)d_out);
}

// Round 4
// 922.790 us; speedup vs baseline: 3.4827x; 1.3816x over previous
//
#include <hip/hip_runtime.h>
#include <math.h>

#define NB 16
#define HH 80
#define WW 60
#define HWSZ (HH * WW)        // 4800
#define CC 256
#define MTOT (NB * HWSZ)      // 76800
#define KVF (16 * 8 * 32 * 32)
#define KSF (16 * 8 * 32)
#define BUF ((size_t)MTOT * CC)   // 19,660,800 elements

typedef unsigned short u16;
typedef __attribute__((ext_vector_type(8))) short short8;
typedef __attribute__((ext_vector_type(4))) float floatx4;

__device__ __forceinline__ float bf2f(u16 u) {
    union { unsigned int i; float f; } v; v.i = ((unsigned int)u) << 16; return v.f;
}
__device__ __forceinline__ u16 f2bf(float f) {
    union { unsigned int i; float f; } v; v.f = f;
    unsigned int u = v.i;
    u += 0x7FFFu + ((u >> 16) & 1u);          // round-to-nearest-even
    return (u16)(u >> 16);
}
__device__ __forceinline__ float elu1(float x) { return x > 0.f ? x + 1.f : expf(x); }

// PE value for channel c at spatial index l (quirk: div[j] = exp(-2j))
__device__ __forceinline__ float pe_val(int c, int l) {
    const int h = l / WW, w = l - h * WW;
    const int j = c >> 2, sel = c & 3;
    const float dv = expf(-2.0f * (float)j);
    const float pos = (sel < 2) ? (float)(w + 1) : (float)(h + 1);
    const float arg = pos * dv;
    return (sel & 1) ? cosf(arg) : sinf(arg);
}

// ---------------- PE add + [N,C,HW] -> [N,HW,C]; fp32 out optional, bf16 out always ----------------
__global__ __launch_bounds__(256) void add_pe_transpose(const float* __restrict__ in,
                                                        float* __restrict__ outf,
                                                        u16* __restrict__ outb)
{
    __shared__ float tile[32][33];
    const int n = blockIdx.z;
    const int c0 = blockIdx.y * 32;
    const int l0 = blockIdx.x * 32;
    const int tx = threadIdx.x, ty = threadIdx.y;
#pragma unroll
    for (int i = 0; i < 4; ++i) {
        const int cl = ty + i * 8;
        tile[cl][tx] = in[(size_t)n * CC * HWSZ + (size_t)(c0 + cl) * HWSZ + l0 + tx];
    }
    __syncthreads();
#pragma unroll
    for (int i = 0; i < 4; ++i) {
        const int ll = ty + i * 8;
        const int l = l0 + ll;
        const int c = c0 + tx;
        const float val = tile[tx][ll] + pe_val(c, l);
        const size_t idx = ((size_t)n * HWSZ + l) * CC + c;
        if (outf) outf[idx] = val;
        outb[idx] = f2bf(val);
    }
}

// ---------------- [N,HW,C] fp32 -> [N,C,HW] fp32 ----------------
__global__ __launch_bounds__(256) void out_transpose(const float* __restrict__ in,
                                                     float* __restrict__ out)
{
    __shared__ float tile[32][33];
    const int n = blockIdx.z;
    const int c0 = blockIdx.y * 32;
    const int l0 = blockIdx.x * 32;
    const int tx = threadIdx.x, ty = threadIdx.y;
#pragma unroll
    for (int i = 0; i < 4; ++i) {
        const int ll = ty + i * 8;
        tile[ll][tx] = in[((size_t)n * HWSZ + l0 + ll) * CC + c0 + tx];
    }
    __syncthreads();
#pragma unroll
    for (int i = 0; i < 4; ++i) {
        const int cl = ty + i * 8;
        out[(size_t)n * CC * HWSZ + (size_t)(c0 + cl) * HWSZ + l0 + tx] = tile[tx][cl];
    }
}

// ---------------- weight fp32 [K,256] -> bf16 transposed [256,K] ----------------
__global__ __launch_bounds__(256) void convert_wt(const float* __restrict__ W,
                                                  u16* __restrict__ WT, int K)
{
    __shared__ float tile[32][33];
    const int k0 = blockIdx.x * 32;
    const int n0 = blockIdx.y * 32;
    const int tx = threadIdx.x, ty = threadIdx.y;
#pragma unroll
    for (int i = 0; i < 4; ++i)
        tile[ty + i * 8][tx] = W[(size_t)(k0 + ty + i * 8) * 256 + n0 + tx];
    __syncthreads();
#pragma unroll
    for (int i = 0; i < 4; ++i)
        WT[(size_t)(n0 + ty + i * 8) * K + k0 + tx] = f2bf(tile[tx][ty + i * 8]);
}

// ---------------- zero small buffer ----------------
__global__ __launch_bounds__(256) void zero_kernel(float* __restrict__ p, int n)
{
    const int i = blockIdx.x * 256 + threadIdx.x;
    if (i < n) p[i] = 0.f;
}

// ---------------- MFMA GEMM: C_bf16[M,256] = act( [A0|A1][M,K]_bf16 @ W[K,256] ) ----------------
__global__ __launch_bounds__(256) void gemm_mfma(const u16* __restrict__ A0,
                                                 const u16* __restrict__ A1,
                                                 const u16* __restrict__ WT,
                                                 u16* __restrict__ C,
                                                 int K, int relu)
{
    __shared__ u16 As[128 * 32];
    __shared__ u16 Bs[128 * 32];
    const int t = threadIdx.x;
    const int row0 = blockIdx.y * 128;
    const int col0 = blockIdx.x * 128;
    const int w = t >> 6, lane = t & 63;
    const int wr = (w >> 1) * 64, wc = (w & 1) * 64;
    const int quad = lane >> 4, lrow = lane & 15;
    const int sm = t >> 2, skc = (t & 3) * 8;

    const floatx4 zero = {0.f, 0.f, 0.f, 0.f};
    floatx4 acc[4][4];
#pragma unroll
    for (int i = 0; i < 4; ++i)
#pragma unroll
        for (int j = 0; j < 4; ++j) acc[i][j] = zero;

    const size_t arow0 = (size_t)(row0 + sm) * 256 + skc;
    const size_t arow1 = (size_t)(row0 + 64 + sm) * 256 + skc;
    const size_t brow0 = (size_t)(col0 + sm) * K + skc;
    const size_t brow1 = (size_t)(col0 + 64 + sm) * K + skc;

    uint4 ra0 = *(const uint4*)(A0 + arow0);
    uint4 ra1 = *(const uint4*)(A0 + arow1);
    uint4 rb0 = *(const uint4*)(WT + brow0);
    uint4 rb1 = *(const uint4*)(WT + brow1);

    for (int k0 = 0; k0 < K; k0 += 32) {
        __syncthreads();
        *(uint4*)&As[sm * 32 + skc] = ra0;
        *(uint4*)&As[(64 + sm) * 32 + skc] = ra1;
        *(uint4*)&Bs[sm * 32 + skc] = rb0;
        *(uint4*)&Bs[(64 + sm) * 32 + skc] = rb1;
        __syncthreads();
        const int kn = k0 + 32;
        if (kn < K) {
            const u16* Abn = (A1 != nullptr && kn >= 256) ? (A1 + (kn - 256)) : (A0 + kn);
            ra0 = *(const uint4*)(Abn + arow0);
            ra1 = *(const uint4*)(Abn + arow1);
            rb0 = *(const uint4*)(WT + brow0 + kn);
            rb1 = *(const uint4*)(WT + brow1 + kn);
        }
        short8 af[4], bfv[4];
#pragma unroll
        for (int i = 0; i < 4; ++i) {
            af[i]  = *(const short8*)&As[(wr + i * 16 + lrow) * 32 + quad * 8];
            bfv[i] = *(const short8*)&Bs[(wc + i * 16 + lrow) * 32 + quad * 8];
        }
#pragma unroll
        for (int i = 0; i < 4; ++i)
#pragma unroll
            for (int j = 0; j < 4; ++j)
                acc[i][j] = __builtin_amdgcn_mfma_f32_16x16x32_bf16(af[i], bfv[j], acc[i][j], 0, 0, 0);
    }

#pragma unroll
    for (int i = 0; i < 4; ++i) {
        const int rbase = row0 + wr + i * 16 + quad * 4;
#pragma unroll
        for (int j = 0; j < 4; ++j) {
            const int cc = col0 + wc + j * 16 + lrow;
#pragma unroll
            for (int r = 0; r < 4; ++r) {
                float x = acc[i][j][r];
                if (relu) x = fmaxf(x, 0.f);
                C[(size_t)(rbase + r) * 256 + cc] = f2bf(x);
            }
        }
    }
}

// ---------------- KV = sum_s K'[s,d] V'[s,e] ; Ksum[d] = sum_s K'[s,d] (bf16 in) ----------------
#define SCHUNK 480
__global__ __launch_bounds__(256) void kv_kernel(const u16* __restrict__ kbuf,
                                                 const u16* __restrict__ vbuf,
                                                 float* __restrict__ KV,
                                                 float* __restrict__ Ksum)
{
    __shared__ float Kls[16][32];
    __shared__ float Vls[16][32];
    const int n = blockIdx.z, h = blockIdx.y;
    const int s0 = blockIdx.x * SCHUNK;
    const int t = threadIdx.x;
    const int lr = t >> 5;
    const int lc = t & 31;
    const int d = t >> 3;
    const int e0 = (t & 7) * 4;
    const float invS = 1.0f / 4800.0f;
    float acc0 = 0.f, acc1 = 0.f, acc2 = 0.f, acc3 = 0.f, ks = 0.f;
    for (int it = 0; it < SCHUNK / 16; ++it) {
        const int sb = s0 + it * 16;
#pragma unroll
        for (int rr = 0; rr < 2; ++rr) {
            const int s = sb + lr + rr * 8;
            const size_t base = ((size_t)(n * HWSZ + s)) * 256 + h * 32 + lc;
            Kls[lr + rr * 8][lc] = elu1(bf2f(kbuf[base]));
            Vls[lr + rr * 8][lc] = bf2f(vbuf[base]) * invS;
        }
        __syncthreads();
#pragma unroll
        for (int ss = 0; ss < 16; ++ss) {
            const float kval = Kls[ss][d];
            acc0 += kval * Vls[ss][e0 + 0];
            acc1 += kval * Vls[ss][e0 + 1];
            acc2 += kval * Vls[ss][e0 + 2];
            acc3 += kval * Vls[ss][e0 + 3];
            if (e0 == 0) ks += kval;
        }
        __syncthreads();
    }
    float* kvp = KV + ((size_t)(n * 8 + h) * 32 + d) * 32 + e0;
    atomicAdd(kvp + 0, acc0);
    atomicAdd(kvp + 1, acc1);
    atomicAdd(kvp + 2, acc2);
    atomicAdd(kvp + 3, acc3);
    if (e0 == 0) atomicAdd(&Ksum[(size_t)(n * 8 + h) * 32 + d], ks);
}

// ---------------- attention apply v2: 32 rows/block, KV in registers ----------------
#define AR 32
__global__ __launch_bounds__(256) void attn_apply(u16* __restrict__ q,
                                                  const float* __restrict__ KV,
                                                  const float* __restrict__ Ksum)
{
    const int row0 = blockIdx.x * AR;      // 4800 % 32 == 0 -> block within one n
    const int n = row0 / HWSZ;
    const int t = threadIdx.x;
    const int h = t >> 5, e = t & 31;
    __shared__ float Qls[AR][256];
    __shared__ float Ks[256];

    // KV column [d][e] for this thread's (h,e) into registers
    float kvr[32];
    const float* kvp = KV + (size_t)(n * 8 + h) * 1024 + e;
#pragma unroll
    for (int d = 0; d < 32; ++d) kvr[d] = kvp[d * 32];
    Ks[t] = Ksum[(size_t)n * 256 + t];

    // stage Q' (elu) rows, vectorized 16B loads
    const int lrow = t >> 5;               // 0..7
    const int lcol = (t & 31) * 8;         // 0..248 step 8
#pragma unroll
    for (int rr = 0; rr < 4; ++rr) {
        const int r = rr * 8 + lrow;
        const ushort4 u0 = *(const ushort4*)&q[(size_t)(row0 + r) * 256 + lcol];
        const ushort4 u1 = *(const ushort4*)&q[(size_t)(row0 + r) * 256 + lcol + 4];
        Qls[r][lcol + 0] = elu1(bf2f(u0.x));
        Qls[r][lcol + 1] = elu1(bf2f(u0.y));
        Qls[r][lcol + 2] = elu1(bf2f(u0.z));
        Qls[r][lcol + 3] = elu1(bf2f(u0.w));
        Qls[r][lcol + 4] = elu1(bf2f(u1.x));
        Qls[r][lcol + 5] = elu1(bf2f(u1.y));
        Qls[r][lcol + 6] = elu1(bf2f(u1.z));
        Qls[r][lcol + 7] = elu1(bf2f(u1.w));
    }
    __syncthreads();

    for (int r = 0; r < AR; ++r) {
        float zden = 1e-6f, acc = 0.f;
#pragma unroll
        for (int d = 0; d < 32; ++d) {
            const float qd = Qls[r][h * 32 + d];   // LDS broadcast
            zden += qd * Ks[h * 32 + d];           // LDS broadcast
            acc += qd * kvr[d];
        }
        q[(size_t)(row0 + r) * 256 + t] = f2bf(acc * (4800.0f / zden));
    }
}

// ---------------- LayerNorm v2: wave-per-row, no barriers ----------------
__device__ __forceinline__ float wave_sum(float v)
{
#pragma unroll
    for (int off = 32; off > 0; off >>= 1) v += __shfl_xor(v, off, 64);
    return v;
}

// 8 rows per wave, 4 waves/block -> 32 rows/block
__global__ __launch_bounds__(256) void ln_inplace(u16* __restrict__ x,
                                                  const float* __restrict__ g,
                                                  const float* __restrict__ b)
{
    const int t = threadIdx.x;
    const int wv = t >> 6, lane = t & 63;
    const int row0 = blockIdx.x * 32 + wv * 8;
    const int c0 = lane * 4;
    const float4 gv = *(const float4*)&g[c0];
    const float4 bv = *(const float4*)&b[c0];
#pragma unroll
    for (int r = 0; r < 8; ++r) {
        const size_t base = (size_t)(row0 + r) * 256 + c0;
        const ushort4 u = *(const ushort4*)&x[base];
        const float v0 = bf2f(u.x), v1 = bf2f(u.y), v2 = bf2f(u.z), v3 = bf2f(u.w);
        const float mu = wave_sum(v0 + v1 + v2 + v3) * (1.0f / 256.0f);
        const float d0 = v0 - mu, d1 = v1 - mu, d2 = v2 - mu, d3 = v3 - mu;
        const float var = wave_sum(d0 * d0 + d1 * d1 + d2 * d2 + d3 * d3) * (1.0f / 256.0f);
        const float rst = rsqrtf(var + 1e-5f);
        ushort4 o;
        o.x = f2bf(d0 * rst * gv.x + bv.x);
        o.y = f2bf(d1 * rst * gv.y + bv.y);
        o.z = f2bf(d2 * rst * gv.z + bv.z);
        o.w = f2bf(d3 * rst * gv.w + bv.w);
        *(ushort4*)&x[base] = o;
    }
}

// LN(x) + residual into fp32 f0, refresh bf16 mirror f0b
__global__ __launch_bounds__(256) void ln_resid(const u16* __restrict__ x,
                                                const float* __restrict__ g,
                                                const float* __restrict__ b,
                                                float* __restrict__ f0,
                                                u16* __restrict__ f0b)
{
    const int t = threadIdx.x;
    const int wv = t >> 6, lane = t & 63;
    const int row0 = blockIdx.x * 32 + wv * 8;
    const int c0 = lane * 4;
    const float4 gv = *(const float4*)&g[c0];
    const float4 bv = *(const float4*)&b[c0];
#pragma unroll
    for (int r = 0; r < 8; ++r) {
        const size_t base = (size_t)(row0 + r) * 256 + c0;
        const ushort4 u = *(const ushort4*)&x[base];
        const float v0 = bf2f(u.x), v1 = bf2f(u.y), v2 = bf2f(u.z), v3 = bf2f(u.w);
        const float mu = wave_sum(v0 + v1 + v2 + v3) * (1.0f / 256.0f);
        const float d0 = v0 - mu, d1 = v1 - mu, d2 = v2 - mu, d3 = v3 - mu;
        const float var = wave_sum(d0 * d0 + d1 * d1 + d2 * d2 + d3 * d3) * (1.0f / 256.0f);
        const float rst = rsqrtf(var + 1e-5f);
        float4 f = *(const float4*)&f0[base];
        f.x += d0 * rst * gv.x + bv.x;
        f.y += d1 * rst * gv.y + bv.y;
        f.z += d2 * rst * gv.z + bv.z;
        f.w += d3 * rst * gv.w + bv.w;
        *(float4*)&f0[base] = f;
        ushort4 o;
        o.x = f2bf(f.x); o.y = f2bf(f.y); o.z = f2bf(f.z); o.w = f2bf(f.w);
        *(ushort4*)&f0b[base] = o;
    }
}

// ---------------- launch ----------------
extern "C" void kernel_launch(void* const* d_in, const int* in_sizes, int n_in,
                              void* d_out, int out_size, void* d_ws, size_t ws_size,
                              hipStream_t stream)
{
    const float* feat0 = (const float*)d_in[0];
    const float* feat1 = (const float*)d_in[1];
    const float* Wq = (const float*)d_in[2];
    const float* Wk = (const float*)d_in[3];
    const float* Wv = (const float*)d_in[4];
    const float* Wm = (const float*)d_in[5];
    const float* W1 = (const float*)d_in[6];
    const float* W2 = (const float*)d_in[7];
    const float* g1 = (const float*)d_in[8];
    const float* b1 = (const float*)d_in[9];
    const float* g2 = (const float*)d_in[10];
    const float* b2 = (const float*)d_in[11];

    float* ws = (float*)d_ws;
    float* KV = ws;
    float* Ksum = KV + KVF;
    u16* Wb = (u16*)(Ksum + KSF);
    const size_t WBE = 458752;
    float* f0 = ws + (KVF + KSF) + WBE;
    u16* f0b = (u16*)(f0 + BUF);
    u16* f1b = f0b + BUF;
    u16* kb16 = (u16*)d_out;
    u16* vb16 = kb16 + BUF;

    const dim3 tb(32, 8);
    const dim3 tgrid(HWSZ / 32, CC / 32, NB);
    add_pe_transpose<<<tgrid, tb, 0, stream>>>(feat0, f0, f0b);
    add_pe_transpose<<<tgrid, tb, 0, stream>>>(feat1, nullptr, f1b);

    for (int i = 0; i < 2; ++i) {
        u16* WqT = Wb + (size_t)i * WBE;
        u16* WkT = WqT + 65536;
        u16* WvT = WkT + 65536;
        u16* WmT = WvT + 65536;
        u16* W1T = WmT + 65536;
        u16* W2T = W1T + 131072;
        convert_wt<<<dim3(8, 8),  tb, 0, stream>>>(Wq + (size_t)i * 65536,  WqT, 256);
        convert_wt<<<dim3(8, 8),  tb, 0, stream>>>(Wk + (size_t)i * 65536,  WkT, 256);
        convert_wt<<<dim3(8, 8),  tb, 0, stream>>>(Wv + (size_t)i * 65536,  WvT, 256);
        convert_wt<<<dim3(8, 8),  tb, 0, stream>>>(Wm + (size_t)i * 65536,  WmT, 256);
        convert_wt<<<dim3(16, 8), tb, 0, stream>>>(W1 + (size_t)i * 131072, W1T, 512);
        convert_wt<<<dim3(8, 8),  tb, 0, stream>>>(W2 + (size_t)i * 65536,  W2T, 256);
    }

    const dim3 ggrid(2, MTOT / 128);
    for (int i = 0; i < 2; ++i) {
        u16* WqT = Wb + (size_t)i * WBE;
        u16* WkT = WqT + 65536;
        u16* WvT = WkT + 65536;
        u16* WmT = WvT + 65536;
        u16* W1T = WmT + 65536;
        u16* W2T = W1T + 131072;

        gemm_mfma<<<ggrid, 256, 0, stream>>>(f1b, nullptr, WkT, kb16, 256, 0);
        gemm_mfma<<<ggrid, 256, 0, stream>>>(f1b, nullptr, WvT, vb16, 256, 0);

        zero_kernel<<<(KVF + KSF + 255) / 256, 256, 0, stream>>>(KV, KVF + KSF);
        kv_kernel<<<dim3(HWSZ / SCHUNK, 8, NB), 256, 0, stream>>>(kb16, vb16, KV, Ksum);

        gemm_mfma<<<ggrid, 256, 0, stream>>>(f0b, nullptr, WqT, kb16, 256, 0);
        attn_apply<<<MTOT / AR, 256, 0, stream>>>(kb16, KV, Ksum);

        gemm_mfma<<<ggrid, 256, 0, stream>>>(kb16, nullptr, WmT, vb16, 256, 0);
        ln_inplace<<<MTOT / 32, 256, 0, stream>>>(vb16, g1 + i * 256, b1 + i * 256);

        gemm_mfma<<<ggrid, 256, 0, stream>>>(f0b, vb16, W1T, kb16, 512, 1);
        gemm_mfma<<<ggrid, 256, 0, stream>>>(kb16, nullptr, W2T, vb16, 256, 0);
        ln_resid<<<MTOT / 32, 256, 0, stream>>>(vb16, g2 + i * 256, b2 + i * 256, f0, f0b);
    }

    out_transpose<<<tgrid, tb, 0, stream>>>(f0, (float*)d_out);
}